// Round 7
// baseline (514.549 us; speedup 1.0000x reference)
//
#include <hip/hip_runtime.h>
#include <hip/hip_bf16.h>
#include <math.h>

// EfficientMambaAttention, round 11: occupancy + launch-count on the non-final mass.
// - k_means v3: flat all-64-lane float4 staging, hsums -> LDS hsS[6400],
//   col sums via LDS atomicAdd. 26KB LDS -> ~6 blocks/CU. Pure BW stream.
// - k_yahw merged into k_xproj launch (block ranges; both post-conv, disjoint).
// - k_post: lt 10->5, grid 256->512 (2 blocks/CU, 8 waves/CU).
// - k_inproj/k_conv/k_scan/k_final unchanged (k_final = r9 floor).

typedef __attribute__((ext_vector_type(8))) short short8;
typedef __attribute__((ext_vector_type(4))) float f32x4;

#define LDS_BARRIER() do { asm volatile("s_waitcnt lgkmcnt(0)" ::: "memory"); \
                           __builtin_amdgcn_s_barrier(); } while(0)

__device__ __forceinline__ float sigm_(float x){ return 1.f/(1.f+__expf(-x)); }
__device__ __forceinline__ float silu_(float x){ return x/(1.f+__expf(-x)); }
__device__ __forceinline__ float gelu_(float x){ return 0.5f*x*(1.f+erff(x*0.7071067811865476f)); }
__device__ __forceinline__ float softplus_(float x){ return (x>20.f)?x:log1pf(__expf(x)); }

// K1 v3: row means -> xh[b,c,h]; col means -> xw[b,c,w].
// Flat coalesced float4 loads (all 64 lanes), hsums to hsS, cols via ds_add.
__global__ __launch_bounds__(256) void k_means(const float* __restrict__ x,
                                               float* __restrict__ xh, float* __restrict__ xw){
  int bc = blockIdx.x;                    // b*128+c
  const float4* xt4 = (const float4*)(x + (size_t)bc*25600); // 6400 float4
  int t = threadIdx.x;
  __shared__ float hsS[6400];             // per-float4 horizontal sums (row-major)
  __shared__ float colacc[160];
  if (t < 160) colacc[t] = 0.f;
  __syncthreads();
  #pragma unroll
  for (int ch=0; ch<5; ch++){
    float4 vv[5];
    #pragma unroll
    for (int j=0;j<5;j++) vv[j] = xt4[(ch*5+j)*256 + t];
    #pragma unroll
    for (int j=0;j<5;j++){
      int idx = (ch*5+j)*256 + t;
      hsS[idx] = (vv[j].x+vv[j].y)+(vv[j].z+vv[j].w);
      int col = (idx % 40)*4;
      atomicAdd(&colacc[col+0], vv[j].x);
      atomicAdd(&colacc[col+1], vv[j].y);
      atomicAdd(&colacc[col+2], vv[j].z);
      atomicAdd(&colacc[col+3], vv[j].w);
    }
  }
  __syncthreads();
  if (t < 160){
    const float4* hr4 = (const float4*)&hsS[t*40];
    float s = 0.f;
    #pragma unroll
    for (int k=0;k<10;k++){
      float4 h4 = hr4[k];
      s += (h4.x+h4.y)+(h4.z+h4.w);
    }
    xh[(size_t)bc*160 + t] = s*(1.f/160.f);
    xw[(size_t)bc*160 + t] = colacc[t]*(1.f/160.f);
  }
}

// K3: in-proj, l-tiled. block=(g,b,lt of 8), 256 thr: thread owns e and e+256.
__global__ __launch_bounds__(256) void k_inproj(
                         const float* __restrict__ xh, const float* __restrict__ xw,
                         const float* __restrict__ inw0, const float* __restrict__ inw1,
                         float* __restrict__ xcpre, float* __restrict__ zb){
  __shared__ float uS[8][128];
  int blk = blockIdx.x;                   // 2*8*20 = 320
  int g = blk/160, rem = blk%160, b = rem/20, lt = rem%20, lbase = lt*8;
  int t = threadIdx.x;
  const float* src = (g==0)? xh : xw;
  {
    int c = t>>1, lh = t&1;
    float4 v = *(const float4*)(src + ((size_t)(b*128+c))*160 + lbase + lh*4);
    uS[lh*4+0][c]=v.x; uS[lh*4+1][c]=v.y; uS[lh*4+2][c]=v.z; uS[lh*4+3][c]=v.w;
  }
  __syncthreads();
  const float* inw = (g==0)? inw0 : inw1;
  const float* w0p = inw + (size_t)t*128;
  const float* w1p = inw + (size_t)(t+256)*128;
  float acc0[8]={0,0,0,0,0,0,0,0}, acc1[8]={0,0,0,0,0,0,0,0};
  for (int ct=0; ct<16; ct++){
    float4 wa = *(const float4*)(w0p + ct*8);
    float4 wb = *(const float4*)(w0p + ct*8 + 4);
    float4 wc = *(const float4*)(w1p + ct*8);
    float4 wd = *(const float4*)(w1p + ct*8 + 4);
    #pragma unroll
    for (int l=0;l<8;l++){
      float4 ua = *(const float4*)&uS[l][ct*8];
      float4 ub = *(const float4*)&uS[l][ct*8+4];
      acc0[l] += wa.x*ua.x + wa.y*ua.y + wa.z*ua.z + wa.w*ua.w
               + wb.x*ub.x + wb.y*ub.y + wb.z*ub.z + wb.w*ub.w;
      acc1[l] += wc.x*ua.x + wc.y*ua.y + wc.z*ua.z + wc.w*ua.w
               + wd.x*ub.x + wd.y*ub.y + wd.z*ub.z + wd.w*ub.w;
    }
  }
  size_t ob = ((size_t)(g*8+b)*160 + lbase)*256;
  #pragma unroll
  for (int l=0;l<8;l++){
    xcpre[ob + (size_t)l*256 + t] = acc0[l];
    zb   [ob + (size_t)l*256 + t] = acc1[l];
  }
}

// K4a: depthwise causal conv(k=4) + bias + silu
__global__ void k_conv(const float* __restrict__ xcpre,
                       const float* __restrict__ cw0, const float* __restrict__ cb0,
                       const float* __restrict__ cw1, const float* __restrict__ cb1,
                       float* __restrict__ xcb){
  int gid = blockIdx.x*blockDim.x + threadIdx.x;
  if (gid >= 2*8*160*256) return;
  int d = gid & 255; int t = gid >> 8; int l = t % 160; int gb = t / 160; int g = gb >> 3;
  const float* cw = ((g==0)? cw0 : cw1) + d*4;
  float acc = ((g==0)? cb0 : cb1)[d];
  const float* base = xcpre + (size_t)gb*160*256 + d;
  #pragma unroll
  for (int k=0;k<4;k++){
    int ls = l-3+k;
    if (ls>=0) acc += cw[k] * base[(size_t)ls*256];
  }
  xcb[gid] = silu_(acc);
}

// K4b merged: blocks [0,160): x-proj (l-tile 16); [160,480): yahw p-blocks;
// [480,608): adjw fp32->bf16 tail. All run post-conv; buffers disjoint.
__global__ __launch_bounds__(256) void k_yx(
                        const float* __restrict__ xcb,
                        const float* __restrict__ xp0, const float* __restrict__ xp1,
                        float* __restrict__ dbc,
                        const float* __restrict__ xh, const float* __restrict__ xw,
                        const float* __restrict__ w1, const float* __restrict__ b1,
                        const float* __restrict__ bg, const float* __restrict__ bb,
                        const float* __restrict__ bm, const float* __restrict__ bv,
                        const float* __restrict__ wh, const float* __restrict__ bh,
                        const float* __restrict__ ww, const float* __restrict__ bw,
                        float* __restrict__ a_h, float* __restrict__ a_w,
                        float* __restrict__ SHT, float* __restrict__ SW,
                        const float* __restrict__ adjw, __hip_bfloat16* __restrict__ adjwb){
  __shared__ float xv[16][260];
  __shared__ float xS[8][128];
  __shared__ float ppart[256];
  __shared__ float yS[8][9];
  int blk = blockIdx.x;
  int t = threadIdx.x;
  if (blk >= 480){
    int i = (blk-480)*256 + t;
    if (i < 32768) adjwb[i] = __float2bfloat16(adjw[i]);
    return;
  }
  if (blk < 160){
    // ---- x-proj role ----
    int g = blk/80, rem = blk%80, b = rem/10, lt = rem%10, lbase = lt*16;
    size_t base = ((size_t)(g*8+b)*160 + lbase)*256;
    for (int i=t; i<4096; i+=256){ int l=i>>8, d=i&255; xv[l][d] = xcb[base+i]; }
    __syncthreads();
    int l = t>>4, s = t&15;
    const float* xp = (g==0)? xp0 : xp1;
    size_t orow = ((size_t)(g*8+b)*160 + lbase + l)*40;
    for (int q=0;q<3;q++){
      int j = s + q*16;
      if (j >= 40) break;
      const float* w = xp + j*256;
      float acc=0.f;
      for (int dd=0; dd<256; dd+=8){
        float4 wa = *(const float4*)(w+dd);
        float4 wb = *(const float4*)(w+dd+4);
        float4 ua = *(const float4*)&xv[l][dd];
        float4 ub = *(const float4*)&xv[l][dd+4];
        acc += wa.x*ua.x + wa.y*ua.y + wa.z*ua.z + wa.w*ua.w
             + wb.x*ub.x + wb.y*ub.y + wb.z*ub.z + wb.w*ub.w;
      }
      dbc[orow + j] = acc;
    }
    return;
  }
  // ---- yahw role ----
  int blk2 = blk - 160;
  int b = blk2/40, pt = blk2%40;
  int p0 = pt*8;
  bool isH = (pt < 20);
  const float* src = isH ? xh : xw;
  int pp0 = isH ? p0 : (p0-160);
  {
    int c = t>>1, h2 = t&1;
    float4 v = *(const float4*)(src + ((size_t)(b*128+c))*160 + pp0 + h2*4);
    xS[h2*4+0][c]=v.x; xS[h2*4+1][c]=v.y; xS[h2*4+2][c]=v.z; xS[h2*4+3][c]=v.w;
  }
  __syncthreads();
  {
    int p8 = t>>5, m = (t>>2)&7, q = t&3;
    const float* wrow = w1 + m*128 + q*32;
    const float* xrow = &xS[p8][q*32];
    float acc = 0.f;
    #pragma unroll
    for (int k4=0;k4<8;k4++){
      float4 wv = *(const float4*)(wrow + k4*4);
      float4 uv = *(const float4*)(xrow + k4*4);
      acc += wv.x*uv.x + wv.y*uv.y + wv.z*uv.z + wv.w*uv.w;
    }
    ppart[t] = acc;
  }
  __syncthreads();
  if (t < 64){
    int p8 = t>>3, m = t&7;
    float val = b1[m] + ppart[t*4+0] + ppart[t*4+1] + ppart[t*4+2] + ppart[t*4+3];
    val = (val - bm[m]) * rsqrtf(bv[m] + 1e-5f);
    val = val * bg[m] + bb[m];
    yS[p8][m] = gelu_(val);
  }
  __syncthreads();
  {
    int c = t&127, pg = t>>7;
    const float* wrow2 = (isH ? wh : ww) + c*8;
    float wreg[8];
    #pragma unroll
    for (int m=0;m<8;m++) wreg[m] = wrow2[m];
    float bias = (isH ? bh : bw)[c];
    float accp[4];
    #pragma unroll
    for (int j=0;j<4;j++){
      int p = pg*4 + j;
      float a = bias;
      #pragma unroll
      for (int m=0;m<8;m++) a += wreg[m]*yS[p][m];
      accp[j] = a;
    }
    size_t rowo = ((size_t)(b*128+c))*160 + pp0 + pg*4;
    if (isH){
      *(float4*)(a_h + rowo) = make_float4(accp[0],accp[1],accp[2],accp[3]);
      #pragma unroll
      for (int j=0;j<4;j++)
        SHT[((size_t)(b*160 + p0 + pg*4 + j))*128 + c] = sigm_(accp[j]);
    } else {
      *(float4*)(a_w + rowo) = make_float4(accp[0],accp[1],accp[2],accp[3]);
      *(float4*)(SW + rowo) = make_float4(sigm_(accp[0]),sigm_(accp[1]),
                                          sigm_(accp[2]),sigm_(accp[3]));
    }
  }
}

// K5: selective scan, LDS-resident. 256 blocks: (gb, dblk of 16 d).
__global__ __launch_bounds__(256) void k_scan(
                       const float* __restrict__ dbc,
                       const float* __restrict__ xcb, const float* __restrict__ zb,
                       const float* __restrict__ dtw0, const float* __restrict__ dtb0,
                       const float* __restrict__ dtw1, const float* __restrict__ dtb1,
                       const float* __restrict__ Alog0, const float* __restrict__ Alog1,
                       const float* __restrict__ D0, const float* __restrict__ D1,
                       float* __restrict__ ysb){
  __shared__ float dsS[160][16];   // delta[l][dloc]
  __shared__ float BS [160][16];   // B[l][n]
  __shared__ float CS [160][16];   // C[l][n]
  __shared__ float xcS[160][16];   // xc[l][dloc]
  __shared__ float yS [160][16];   // y (pre-silu-z) [l][dloc]
  int blk = blockIdx.x;            // gb = blk>>4 (16), dblk = blk&15
  int gb = blk >> 4, dblk = blk & 15, g = gb >> 3;
  int dbase = dblk*16;
  int t = threadIdx.x;
  size_t base = (size_t)gb*160*256;
  const float* db = dbc + (size_t)gb*6400;
  const float* dtwG = (g==0)? dtw0 : dtw1;
  const float* dtbG = (g==0)? dtb0 : dtb1;

  #pragma unroll
  for (int i=0;i<10;i++){
    int item = t + 256*i;          // 2560 = 160 l x 16
    int l = item>>4, c = item&15;
    const float* r = db + l*40;
    int d = dbase + c;
    const float* wt = dtwG + d*8;
    float4 w0 = *(const float4*)wt;
    float4 w1 = *(const float4*)(wt+4);
    float4 r0 = *(const float4*)r;
    float4 r1 = *(const float4*)(r+4);
    float dt = dtbG[d] + w0.x*r0.x+w0.y*r0.y+w0.z*r0.z+w0.w*r0.w
                       + w1.x*r1.x+w1.y*r1.y+w1.z*r1.z+w1.w*r1.w;
    dsS[l][c] = softplus_(dt);
    BS [l][c] = r[8+c];
    CS [l][c] = r[24+c];
    xcS[l][c] = xcb[base + (size_t)l*256 + dbase + c];
  }
  __syncthreads();

  int dloc = t>>4, n = t&15;
  int d = dbase + dloc;
  float A  = -__expf(((g==0)? Alog0 : Alog1)[d*16+n]);
  float Dd = ((g==0)? D0 : D1)[d];
  float h = 0.f;
  for (int lc=0; lc<160; lc+=8){
    float ds8[8], B8[8], C8[8], xc8[8];
    #pragma unroll
    for (int j=0;j<8;j++){
      ds8[j]=dsS[lc+j][dloc]; B8[j]=BS[lc+j][n];
      C8[j]=CS[lc+j][n];      xc8[j]=xcS[lc+j][dloc];
    }
    #pragma unroll
    for (int j=0;j<8;j++){
      float dA = __expf(ds8[j]*A);
      h = dA*h + ds8[j]*B8[j]*xc8[j];
      float p = h*C8[j];
      p += __shfl_xor(p,1,16); p += __shfl_xor(p,2,16);
      p += __shfl_xor(p,4,16); p += __shfl_xor(p,8,16);
      if (n==0) yS[lc+j][dloc] = p + xc8[j]*Dd;
    }
  }
  __syncthreads();

  #pragma unroll
  for (int i=0;i<10;i++){
    int item = t + 256*i;
    int l = item>>4, c = item&15;
    size_t gi = base + (size_t)l*256 + dbase + c;
    ysb[gi] = yS[l][c] * silu_(zb[gi]);
  }
}

// K6 v2: fused outproj+sigmoid + mlp1(gelu) + mlp2. l-tile 5, grid 512 (2 blk/CU).
// g==0 output written TRANSPOSED (QxT[b][l][c]); g==1 -> Qy row-major.
__global__ __launch_bounds__(256) void k_post(
                       const float* __restrict__ ysb,
                       const float* __restrict__ ow0, const float* __restrict__ ow1,
                       const float* __restrict__ a_h, const float* __restrict__ a_w,
                       const float* __restrict__ w1x, const float* __restrict__ b1x,
                       const float* __restrict__ w1y, const float* __restrict__ b1y,
                       const float* __restrict__ w2x, const float* __restrict__ b2x,
                       const float* __restrict__ w2y, const float* __restrict__ b2y,
                       float* __restrict__ QxT, float* __restrict__ Qy){
  __shared__ float ysS[5][256];
  __shared__ float Sc[5][128];
  __shared__ float Sp[5][128];
  int blk = blockIdx.x;                   // 2*8*32 = 512
  int g = blk>>8, rem = blk&255, b = rem>>5, lt = rem&31, lbase = lt*5;
  int t = threadIdx.x; int c = t&127, kh = t>>7;
  size_t ybase = ((size_t)(g*8+b)*160 + lbase)*256;
  for (int i=t; i<1280; i+=256) ((float*)ysS)[i] = ysb[ybase+i];
  __syncthreads();
  float acc[5];
  // ---- out-proj (K=256 split 2x128) ----
  {
    const float* w = ((g==0)? ow0 : ow1) + (size_t)c*256 + kh*128;
    #pragma unroll
    for (int l=0;l<5;l++) acc[l]=0.f;
    for (int ct=0; ct<16; ct++){
      float4 wa = *(const float4*)(w + ct*8);
      float4 wb = *(const float4*)(w + ct*8 + 4);
      #pragma unroll
      for (int l=0;l<5;l++){
        float4 ua = *(const float4*)&ysS[l][kh*128+ct*8];
        float4 ub = *(const float4*)&ysS[l][kh*128+ct*8+4];
        acc[l] += wa.x*ua.x + wa.y*ua.y + wa.z*ua.z + wa.w*ua.w
                + wb.x*ub.x + wb.y*ub.y + wb.z*ub.z + wb.w*ub.w;
      }
    }
  }
  if (kh==1){ for (int l=0;l<5;l++) Sc[l][c] = acc[l]; }
  __syncthreads();
  if (kh==0){
    const float* a = ((g==0)? a_h : a_w) + ((size_t)(b*128+c))*160 + lbase;
    #pragma unroll
    for (int l=0;l<5;l++) Sp[l][c] = sigm_(acc[l] + Sc[l][c] + a[l]);
  }
  __syncthreads();
  // ---- mlp1 (K=128 split 2x64), gelu ----
  {
    const float* w = ((g==0)? w1x : w1y) + (size_t)c*128 + kh*64;
    #pragma unroll
    for (int l=0;l<5;l++) acc[l]=0.f;
    for (int ct=0; ct<8; ct++){
      float4 wa = *(const float4*)(w + ct*8);
      float4 wb = *(const float4*)(w + ct*8 + 4);
      #pragma unroll
      for (int l=0;l<5;l++){
        float4 ua = *(const float4*)&Sp[l][kh*64+ct*8];
        float4 ub = *(const float4*)&Sp[l][kh*64+ct*8+4];
        acc[l] += wa.x*ua.x + wa.y*ua.y + wa.z*ua.z + wa.w*ua.w
                + wb.x*ub.x + wb.y*ub.y + wb.z*ub.z + wb.w*ub.w;
      }
    }
  }
  if (kh==1){ for (int l=0;l<5;l++) Sc[l][c] = acc[l]; }
  __syncthreads();
  if (kh==0){
    float bb = ((g==0)? b1x : b1y)[c];
    float tv[5];
    #pragma unroll
    for (int l=0;l<5;l++) tv[l] = gelu_(bb + acc[l] + Sc[l][c]);
    __syncthreads();
    #pragma unroll
    for (int l=0;l<5;l++) Sp[l][c] = tv[l];
  } else {
    __syncthreads();
  }
  __syncthreads();
  // ---- mlp2 (K=128 split 2x64) ----
  {
    const float* w = ((g==0)? w2x : w2y) + (size_t)c*128 + kh*64;
    #pragma unroll
    for (int l=0;l<5;l++) acc[l]=0.f;
    for (int ct=0; ct<8; ct++){
      float4 wa = *(const float4*)(w + ct*8);
      float4 wb = *(const float4*)(w + ct*8 + 4);
      #pragma unroll
      for (int l=0;l<5;l++){
        float4 ua = *(const float4*)&Sp[l][kh*64+ct*8];
        float4 ub = *(const float4*)&Sp[l][kh*64+ct*8+4];
        acc[l] += wa.x*ua.x + wa.y*ua.y + wa.z*ua.z + wa.w*ua.w
                + wb.x*ub.x + wb.y*ub.y + wb.z*ub.z + wb.w*ub.w;
      }
    }
  }
  if (kh==1){ for (int l=0;l<5;l++) Sc[l][c] = acc[l]; }
  __syncthreads();
  if (kh==0){
    float bb = ((g==0)? b2x : b2y)[c];
    if (g==0){
      #pragma unroll
      for (int l=0;l<5;l++)
        QxT[((size_t)(b*160 + lbase + l))*128 + c] = bb + acc[l] + Sc[l][c];
    } else {
      size_t orow = ((size_t)(b*128+c))*160 + lbase;
      #pragma unroll
      for (int l=0;l<5;l++) Qy[orow + l] = bb + acc[l] + Sc[l][c];
    }
  }
}

// helper: scale 4-float4 panel regs by gate, write one LDS F buffer [32w][136]
__device__ __forceinline__ void build_F(__hip_bfloat16* Fb, float s, const float4* v,
                                        int wg, int kq){
  #pragma unroll
  for (int u=0;u<4;u++){
    int wr = wg*16 + u*4;
    Fb[(wr+0)*136 + kq] = __float2bfloat16(s*v[u].x);
    Fb[(wr+1)*136 + kq] = __float2bfloat16(s*v[u].y);
    Fb[(wr+2)*136 + kq] = __float2bfloat16(s*v[u].z);
    Fb[(wr+3)*136 + kq] = __float2bfloat16(s*v[u].w);
  }
}

// K7 v5 (MFMA, small-tile + LDS-only barriers) — unchanged from round 9.
__global__ __launch_bounds__(256,4) void k_final_mfma(
                       const float* __restrict__ x,
                       const float* __restrict__ SHT, const float* __restrict__ SW,
                       const float* __restrict__ QxT, const float* __restrict__ Qy,
                       const __hip_bfloat16* __restrict__ adjwb, float* __restrict__ out){
  __shared__ __hip_bfloat16 F[2][32*136];  // double buffer, 2x8.5KB
  int blk0 = blockIdx.x;                   // 1280 = 8 XCD * 160
  int b = blk0 & 7, inner = blk0 >> 3;     // batch b pinned to XCD b
  int ht = inner/5, wq = inner%5;          // ht 0..31, wq 0..4
  int h0 = ht*5;
  int wbase = wq*32;
  int tid = threadIdx.x;
  int kq = tid & 127, wg = tid >> 7;       // staging: k row, w sub-half (16 w)
  int wid = tid>>6, lane = tid&63, quad = lane>>4, l16 = lane&15;

  // gates for the 5 h (coalesced 512B rows)
  float s0[5], s1[5];
  #pragma unroll
  for (int j=0;j<5;j++){
    s0[j] = SHT[((size_t)(b*160+h0+j))*128 + kq];
    s1[j] = QxT[((size_t)(b*160+h0+j))*128 + kq];
  }
  // panels: 4+4 float4, loaded once, reused for all 5 h
  size_t prow = ((size_t)(b*128+kq))*160 + wbase + wg*16;
  const float4* rp0 = (const float4*)(Qy + prow);
  const float4* rp1 = (const float4*)(SW + prow);
  float4 v0[4], v1[4];
  #pragma unroll
  for (int u=0;u<4;u++) v0[u] = rp0[u];
  #pragma unroll
  for (int u=0;u<4;u++) v1[u] = rp1[u];

  build_F(F[0], s0[0], v0, wg, kq);
  LDS_BARRIER();

  // o-row base addresses (o = wid*32 + i*16 + l16)
  size_t rowA = ((size_t)(b*128 + wid*32 + l16))*25600 + wbase + quad*4;
  size_t rowB = rowA + (size_t)16*25600;

  #pragma unroll
  for (int j=0;j<5;j++){
    int h = h0 + j;
    // x prefetch for this h (consumed after MFMA ch1; spans LDS barriers)
    float4 xv[2][2];
    #pragma unroll
    for (int nt=0;nt<2;nt++){
      xv[0][nt] = *(const float4*)(x + rowA + (size_t)h*160 + nt*16);
      xv[1][nt] = *(const float4*)(x + rowB + (size_t)h*160 + nt*16);
    }
    f32x4 acc[2][2];
    #pragma unroll
    for (int i=0;i<2;i++)
      #pragma unroll
      for (int nt=0;nt<2;nt++) acc[i][nt] = (f32x4){0.f,0.f,0.f,0.f};

    // ---- MFMA ch0 (reads F[0]) ----
    {
      short8 bf[2][4];
      #pragma unroll
      for (int i=0;i<2;i++){
        const __hip_bfloat16* bp = adjwb + (size_t)(wid*32 + i*16 + l16)*256 + quad*8;
        #pragma unroll
        for (int kc=0;kc<4;kc++) bf[i][kc] = *(const short8*)(bp + kc*32);
      }
      #pragma unroll
      for (int nt=0; nt<2; nt++){
        const __hip_bfloat16* ap = &F[0][(nt*16 + l16)*136 + quad*8];
        #pragma unroll
        for (int kc=0;kc<4;kc++){
          short8 af = *(const short8*)(ap + kc*32);
          acc[0][nt] = __builtin_amdgcn_mfma_f32_16x16x32_bf16(af, bf[0][kc], acc[0][nt], 0,0,0);
          acc[1][nt] = __builtin_amdgcn_mfma_f32_16x16x32_bf16(af, bf[1][kc], acc[1][nt], 0,0,0);
        }
      }
    }
    // build F[1] = ch1 of this h (F[1] readers finished before last barrier)
    build_F(F[1], s1[j], v1, wg, kq);
    LDS_BARRIER();     // F[1] ready; all waves done reading F[0]

    // ---- MFMA ch1 (reads F[1]) ----
    {
      short8 bf[2][4];
      #pragma unroll
      for (int i=0;i<2;i++){
        const __hip_bfloat16* bp = adjwb + (size_t)(wid*32 + i*16 + l16)*256 + 128 + quad*8;
        #pragma unroll
        for (int kc=0;kc<4;kc++) bf[i][kc] = *(const short8*)(bp + kc*32);
      }
      #pragma unroll
      for (int nt=0; nt<2; nt++){
        const __hip_bfloat16* ap = &F[1][(nt*16 + l16)*136 + quad*8];
        #pragma unroll
        for (int kc=0;kc<4;kc++){
          short8 af = *(const short8*)(ap + kc*32);
          acc[0][nt] = __builtin_amdgcn_mfma_f32_16x16x32_bf16(af, bf[0][kc], acc[0][nt], 0,0,0);
          acc[1][nt] = __builtin_amdgcn_mfma_f32_16x16x32_bf16(af, bf[1][kc], acc[1][nt], 0,0,0);
        }
      }
    }
    // build F[0] for next h (F[0] readers finished before last barrier)
    if (j<4) build_F(F[0], s0[j+1], v0, wg, kq);

    // ---- epilogue: multiply prefetched x, plain float4 stores ----
    #pragma unroll
    for (int i=0;i<2;i++){
      size_t rb = (i? rowB : rowA) + (size_t)h*160;
      #pragma unroll
      for (int nt=0; nt<2; nt++){
        f32x4 a = acc[i][nt];
        float4 xvv = xv[i][nt];
        float4 ov = make_float4(xvv.x*a[0], xvv.y*a[1], xvv.z*a[2], xvv.w*a[3]);
        *(float4*)(out + rb + nt*16) = ov;
      }
    }
    LDS_BARRIER();     // F[0]/F[1] safe for next iter; global ops NOT drained
  }
}

extern "C" void kernel_launch(void* const* d_in, const int* in_sizes, int n_in,
                              void* d_out, int out_size, void* d_ws, size_t ws_size,
                              hipStream_t stream) {
  #define W(i) ((const float*)d_in[i])
  const float* X = W(0);
  float* ws = (float*)d_ws;
  float* xh    = ws;               // 163840
  float* xw    = xh    + 163840;   // 163840
  float* ybuf  = xw    + 163840;   // 20480 (unused; slot kept)
  float* ah    = ybuf  + 20480;    // 163840
  float* aw    = ah    + 163840;   // 163840
  float* xcpre = aw    + 163840;   // 655360 (dead after k_conv; adjwb/SHT/SW alias it)
  float* zb    = xcpre + 655360;   // 655360
  float* xcb   = zb    + 655360;   // 655360
  float* dbc   = xcb   + 655360;   // 102400
  float* ysb   = dbc   + 102400;   // 655360
  float* QxT   = ysb   + 655360;   // 163840 (transposed [b][l][c])
  float* Qy    = QxT   + 163840;   // 163840
  __hip_bfloat16* adjwb = (__hip_bfloat16*)xcpre;  // 64KB = 16384 floats
  float* SHT   = xcpre + 16384;    // 163840 (sigm(a_h), transposed [b][h][c])
  float* SW    = SHT   + 163840;   // 163840 (sigm(a_w), row-major [b][c][w])

  k_means  <<<1024, 256, 0, stream>>>(X, xh, xw);
  k_inproj <<<320,  256, 0, stream>>>(xh, xw, W(20), W(29), xcpre, zb);
  k_conv   <<<2560, 256, 0, stream>>>(xcpre, W(21), W(22), W(30), W(31), xcb);
  k_yx     <<<608,  256, 0, stream>>>(xcb, W(23), W(32), dbc,
                                      xh, xw, W(1), W(2), W(3), W(4), W(5), W(6),
                                      W(7), W(8), W(9), W(10), ah, aw, SHT, SW,
                                      W(19), adjwb);  // after k_conv (xcpre dead)
  k_scan   <<<256,  256, 0, stream>>>(dbc, xcb, zb, W(24), W(25), W(33), W(34),
                                      W(26), W(35), W(27), W(36), ysb);
  k_post   <<<512,  256, 0, stream>>>(ysb, W(28), W(37), ah, aw,
                                      W(11), W(12), W(15), W(16),
                                      W(13), W(14), W(17), W(18), QxT, Qy);
  k_final_mfma<<<1280, 256, 0, stream>>>(X, SHT, SW, QxT, Qy, adjwb, (float*)d_out);
  #undef W
}

// Round 8
// 415.720 us; speedup vs baseline: 1.2377x; 1.2377x over previous
//
#include <hip/hip_runtime.h>
#include <hip/hip_bf16.h>
#include <math.h>

// EfficientMambaAttention, round 12: fix k_means regression (r11 post-mortem:
// LDS atomicAdd chain = 25600 serializing atomics/block -> 137us, VALUBusy 1.4%).
// k_means v4: block=320 (320 % 40 == 0 -> each thread's float4-column is FIXED
// -> column sums accumulate in a register float4, no atomics). Row partials to
// hsS[row*41+k] (2-way bank alias, free). All-lane coalesced flat loads.
// k_yx merge + k_post lt=5 kept from r11 (neutral). k_final = r9 floor.

typedef __attribute__((ext_vector_type(8))) short short8;
typedef __attribute__((ext_vector_type(4))) float f32x4;

#define LDS_BARRIER() do { asm volatile("s_waitcnt lgkmcnt(0)" ::: "memory"); \
                           __builtin_amdgcn_s_barrier(); } while(0)

__device__ __forceinline__ float sigm_(float x){ return 1.f/(1.f+__expf(-x)); }
__device__ __forceinline__ float silu_(float x){ return x/(1.f+__expf(-x)); }
__device__ __forceinline__ float gelu_(float x){ return 0.5f*x*(1.f+erff(x*0.7071067811865476f)); }
__device__ __forceinline__ float softplus_(float x){ return (x>20.f)?x:log1pf(__expf(x)); }

// K1 v4: row means -> xh[b,c,h]; col means -> xw[b,c,w]. Block = 320 threads.
// Flat idx = i*320+t over 6400 float4s: idx%40 == t%40 (fixed col4/thread) ->
// col sums in a register float4; row hsums -> hsS[row*41+k]. No atomics.
__global__ __launch_bounds__(320) void k_means(const float* __restrict__ x,
                                               float* __restrict__ xh, float* __restrict__ xw){
  int bc = blockIdx.x;                    // b*128+c
  const float4* xt4 = (const float4*)(x + (size_t)bc*25600); // 6400 float4
  int t = threadIdx.x;                    // 0..319
  int t40 = t/40, tm40 = t%40;
  __shared__ float hsS[160*41];           // 26.2KB row partials (stride 41)
  __shared__ float4 colpart[8][40];       // 5.1KB
  float4 ca = make_float4(0.f,0.f,0.f,0.f);
  int hbase = t40*41 + tm40;
  #pragma unroll
  for (int i=0;i<20;i++){
    float4 v = xt4[i*320 + t];            // fully coalesced (1280B per 320-thread span)
    ca.x+=v.x; ca.y+=v.y; ca.z+=v.z; ca.w+=v.w;
    hsS[hbase + i*328] = (v.x+v.y)+(v.z+v.w);   // row = i*8+t40, k = tm40
  }
  colpart[t40][tm40] = ca;
  __syncthreads();
  if (t < 160){
    const float* hr = &hsS[t*41];
    float s = 0.f;
    #pragma unroll
    for (int k=0;k<40;k++) s += hr[k];
    xh[(size_t)bc*160 + t] = s*(1.f/160.f);
  }
  if (t < 40){
    float4 s = colpart[0][t];
    #pragma unroll
    for (int r=1;r<8;r++){
      float4 p = colpart[r][t];
      s.x+=p.x; s.y+=p.y; s.z+=p.z; s.w+=p.w;
    }
    ((float4*)(xw + (size_t)bc*160))[t] =
      make_float4(s.x*(1.f/160.f), s.y*(1.f/160.f), s.z*(1.f/160.f), s.w*(1.f/160.f));
  }
}

// K3: in-proj, l-tiled. block=(g,b,lt of 8), 256 thr: thread owns e and e+256.
__global__ __launch_bounds__(256) void k_inproj(
                         const float* __restrict__ xh, const float* __restrict__ xw,
                         const float* __restrict__ inw0, const float* __restrict__ inw1,
                         float* __restrict__ xcpre, float* __restrict__ zb){
  __shared__ float uS[8][128];
  int blk = blockIdx.x;                   // 2*8*20 = 320
  int g = blk/160, rem = blk%160, b = rem/20, lt = rem%20, lbase = lt*8;
  int t = threadIdx.x;
  const float* src = (g==0)? xh : xw;
  {
    int c = t>>1, lh = t&1;
    float4 v = *(const float4*)(src + ((size_t)(b*128+c))*160 + lbase + lh*4);
    uS[lh*4+0][c]=v.x; uS[lh*4+1][c]=v.y; uS[lh*4+2][c]=v.z; uS[lh*4+3][c]=v.w;
  }
  __syncthreads();
  const float* inw = (g==0)? inw0 : inw1;
  const float* w0p = inw + (size_t)t*128;
  const float* w1p = inw + (size_t)(t+256)*128;
  float acc0[8]={0,0,0,0,0,0,0,0}, acc1[8]={0,0,0,0,0,0,0,0};
  for (int ct=0; ct<16; ct++){
    float4 wa = *(const float4*)(w0p + ct*8);
    float4 wb = *(const float4*)(w0p + ct*8 + 4);
    float4 wc = *(const float4*)(w1p + ct*8);
    float4 wd = *(const float4*)(w1p + ct*8 + 4);
    #pragma unroll
    for (int l=0;l<8;l++){
      float4 ua = *(const float4*)&uS[l][ct*8];
      float4 ub = *(const float4*)&uS[l][ct*8+4];
      acc0[l] += wa.x*ua.x + wa.y*ua.y + wa.z*ua.z + wa.w*ua.w
               + wb.x*ub.x + wb.y*ub.y + wb.z*ub.z + wb.w*ub.w;
      acc1[l] += wc.x*ua.x + wc.y*ua.y + wc.z*ua.z + wc.w*ua.w
               + wd.x*ub.x + wd.y*ub.y + wd.z*ub.z + wd.w*ub.w;
    }
  }
  size_t ob = ((size_t)(g*8+b)*160 + lbase)*256;
  #pragma unroll
  for (int l=0;l<8;l++){
    xcpre[ob + (size_t)l*256 + t] = acc0[l];
    zb   [ob + (size_t)l*256 + t] = acc1[l];
  }
}

// K4a: depthwise causal conv(k=4) + bias + silu
__global__ void k_conv(const float* __restrict__ xcpre,
                       const float* __restrict__ cw0, const float* __restrict__ cb0,
                       const float* __restrict__ cw1, const float* __restrict__ cb1,
                       float* __restrict__ xcb){
  int gid = blockIdx.x*blockDim.x + threadIdx.x;
  if (gid >= 2*8*160*256) return;
  int d = gid & 255; int t = gid >> 8; int l = t % 160; int gb = t / 160; int g = gb >> 3;
  const float* cw = ((g==0)? cw0 : cw1) + d*4;
  float acc = ((g==0)? cb0 : cb1)[d];
  const float* base = xcpre + (size_t)gb*160*256 + d;
  #pragma unroll
  for (int k=0;k<4;k++){
    int ls = l-3+k;
    if (ls>=0) acc += cw[k] * base[(size_t)ls*256];
  }
  xcb[gid] = silu_(acc);
}

// K4b merged: blocks [0,160): x-proj (l-tile 16); [160,480): yahw p-blocks;
// [480,608): adjw fp32->bf16 tail. All run post-conv; buffers disjoint.
__global__ __launch_bounds__(256) void k_yx(
                        const float* __restrict__ xcb,
                        const float* __restrict__ xp0, const float* __restrict__ xp1,
                        float* __restrict__ dbc,
                        const float* __restrict__ xh, const float* __restrict__ xw,
                        const float* __restrict__ w1, const float* __restrict__ b1,
                        const float* __restrict__ bg, const float* __restrict__ bb,
                        const float* __restrict__ bm, const float* __restrict__ bv,
                        const float* __restrict__ wh, const float* __restrict__ bh,
                        const float* __restrict__ ww, const float* __restrict__ bw,
                        float* __restrict__ a_h, float* __restrict__ a_w,
                        float* __restrict__ SHT, float* __restrict__ SW,
                        const float* __restrict__ adjw, __hip_bfloat16* __restrict__ adjwb){
  __shared__ float xv[16][260];
  __shared__ float xS[8][128];
  __shared__ float ppart[256];
  __shared__ float yS[8][9];
  int blk = blockIdx.x;
  int t = threadIdx.x;
  if (blk >= 480){
    int i = (blk-480)*256 + t;
    if (i < 32768) adjwb[i] = __float2bfloat16(adjw[i]);
    return;
  }
  if (blk < 160){
    // ---- x-proj role ----
    int g = blk/80, rem = blk%80, b = rem/10, lt = rem%10, lbase = lt*16;
    size_t base = ((size_t)(g*8+b)*160 + lbase)*256;
    for (int i=t; i<4096; i+=256){ int l=i>>8, d=i&255; xv[l][d] = xcb[base+i]; }
    __syncthreads();
    int l = t>>4, s = t&15;
    const float* xp = (g==0)? xp0 : xp1;
    size_t orow = ((size_t)(g*8+b)*160 + lbase + l)*40;
    for (int q=0;q<3;q++){
      int j = s + q*16;
      if (j >= 40) break;
      const float* w = xp + j*256;
      float acc=0.f;
      for (int dd=0; dd<256; dd+=8){
        float4 wa = *(const float4*)(w+dd);
        float4 wb = *(const float4*)(w+dd+4);
        float4 ua = *(const float4*)&xv[l][dd];
        float4 ub = *(const float4*)&xv[l][dd+4];
        acc += wa.x*ua.x + wa.y*ua.y + wa.z*ua.z + wa.w*ua.w
             + wb.x*ub.x + wb.y*ub.y + wb.z*ub.z + wb.w*ub.w;
      }
      dbc[orow + j] = acc;
    }
    return;
  }
  // ---- yahw role ----
  int blk2 = blk - 160;
  int b = blk2/40, pt = blk2%40;
  int p0 = pt*8;
  bool isH = (pt < 20);
  const float* src = isH ? xh : xw;
  int pp0 = isH ? p0 : (p0-160);
  {
    int c = t>>1, h2 = t&1;
    float4 v = *(const float4*)(src + ((size_t)(b*128+c))*160 + pp0 + h2*4);
    xS[h2*4+0][c]=v.x; xS[h2*4+1][c]=v.y; xS[h2*4+2][c]=v.z; xS[h2*4+3][c]=v.w;
  }
  __syncthreads();
  {
    int p8 = t>>5, m = (t>>2)&7, q = t&3;
    const float* wrow = w1 + m*128 + q*32;
    const float* xrow = &xS[p8][q*32];
    float acc = 0.f;
    #pragma unroll
    for (int k4=0;k4<8;k4++){
      float4 wv = *(const float4*)(wrow + k4*4);
      float4 uv = *(const float4*)(xrow + k4*4);
      acc += wv.x*uv.x + wv.y*uv.y + wv.z*uv.z + wv.w*uv.w;
    }
    ppart[t] = acc;
  }
  __syncthreads();
  if (t < 64){
    int p8 = t>>3, m = t&7;
    float val = b1[m] + ppart[t*4+0] + ppart[t*4+1] + ppart[t*4+2] + ppart[t*4+3];
    val = (val - bm[m]) * rsqrtf(bv[m] + 1e-5f);
    val = val * bg[m] + bb[m];
    yS[p8][m] = gelu_(val);
  }
  __syncthreads();
  {
    int c = t&127, pg = t>>7;
    const float* wrow2 = (isH ? wh : ww) + c*8;
    float wreg[8];
    #pragma unroll
    for (int m=0;m<8;m++) wreg[m] = wrow2[m];
    float bias = (isH ? bh : bw)[c];
    float accp[4];
    #pragma unroll
    for (int j=0;j<4;j++){
      int p = pg*4 + j;
      float a = bias;
      #pragma unroll
      for (int m=0;m<8;m++) a += wreg[m]*yS[p][m];
      accp[j] = a;
    }
    size_t rowo = ((size_t)(b*128+c))*160 + pp0 + pg*4;
    if (isH){
      *(float4*)(a_h + rowo) = make_float4(accp[0],accp[1],accp[2],accp[3]);
      #pragma unroll
      for (int j=0;j<4;j++)
        SHT[((size_t)(b*160 + p0 + pg*4 + j))*128 + c] = sigm_(accp[j]);
    } else {
      *(float4*)(a_w + rowo) = make_float4(accp[0],accp[1],accp[2],accp[3]);
      *(float4*)(SW + rowo) = make_float4(sigm_(accp[0]),sigm_(accp[1]),
                                          sigm_(accp[2]),sigm_(accp[3]));
    }
  }
}

// K5: selective scan, LDS-resident. 256 blocks: (gb, dblk of 16 d).
__global__ __launch_bounds__(256) void k_scan(
                       const float* __restrict__ dbc,
                       const float* __restrict__ xcb, const float* __restrict__ zb,
                       const float* __restrict__ dtw0, const float* __restrict__ dtb0,
                       const float* __restrict__ dtw1, const float* __restrict__ dtb1,
                       const float* __restrict__ Alog0, const float* __restrict__ Alog1,
                       const float* __restrict__ D0, const float* __restrict__ D1,
                       float* __restrict__ ysb){
  __shared__ float dsS[160][16];   // delta[l][dloc]
  __shared__ float BS [160][16];   // B[l][n]
  __shared__ float CS [160][16];   // C[l][n]
  __shared__ float xcS[160][16];   // xc[l][dloc]
  __shared__ float yS [160][16];   // y (pre-silu-z) [l][dloc]
  int blk = blockIdx.x;            // gb = blk>>4 (16), dblk = blk&15
  int gb = blk >> 4, dblk = blk & 15, g = gb >> 3;
  int dbase = dblk*16;
  int t = threadIdx.x;
  size_t base = (size_t)gb*160*256;
  const float* db = dbc + (size_t)gb*6400;
  const float* dtwG = (g==0)? dtw0 : dtw1;
  const float* dtbG = (g==0)? dtb0 : dtb1;

  #pragma unroll
  for (int i=0;i<10;i++){
    int item = t + 256*i;          // 2560 = 160 l x 16
    int l = item>>4, c = item&15;
    const float* r = db + l*40;
    int d = dbase + c;
    const float* wt = dtwG + d*8;
    float4 w0 = *(const float4*)wt;
    float4 w1 = *(const float4*)(wt+4);
    float4 r0 = *(const float4*)r;
    float4 r1 = *(const float4*)(r+4);
    float dt = dtbG[d] + w0.x*r0.x+w0.y*r0.y+w0.z*r0.z+w0.w*r0.w
                       + w1.x*r1.x+w1.y*r1.y+w1.z*r1.z+w1.w*r1.w;
    dsS[l][c] = softplus_(dt);
    BS [l][c] = r[8+c];
    CS [l][c] = r[24+c];
    xcS[l][c] = xcb[base + (size_t)l*256 + dbase + c];
  }
  __syncthreads();

  int dloc = t>>4, n = t&15;
  int d = dbase + dloc;
  float A  = -__expf(((g==0)? Alog0 : Alog1)[d*16+n]);
  float Dd = ((g==0)? D0 : D1)[d];
  float h = 0.f;
  for (int lc=0; lc<160; lc+=8){
    float ds8[8], B8[8], C8[8], xc8[8];
    #pragma unroll
    for (int j=0;j<8;j++){
      ds8[j]=dsS[lc+j][dloc]; B8[j]=BS[lc+j][n];
      C8[j]=CS[lc+j][n];      xc8[j]=xcS[lc+j][dloc];
    }
    #pragma unroll
    for (int j=0;j<8;j++){
      float dA = __expf(ds8[j]*A);
      h = dA*h + ds8[j]*B8[j]*xc8[j];
      float p = h*C8[j];
      p += __shfl_xor(p,1,16); p += __shfl_xor(p,2,16);
      p += __shfl_xor(p,4,16); p += __shfl_xor(p,8,16);
      if (n==0) yS[lc+j][dloc] = p + xc8[j]*Dd;
    }
  }
  __syncthreads();

  #pragma unroll
  for (int i=0;i<10;i++){
    int item = t + 256*i;
    int l = item>>4, c = item&15;
    size_t gi = base + (size_t)l*256 + dbase + c;
    ysb[gi] = yS[l][c] * silu_(zb[gi]);
  }
}

// K6 v2: fused outproj+sigmoid + mlp1(gelu) + mlp2. l-tile 5, grid 512 (2 blk/CU).
// g==0 output written TRANSPOSED (QxT[b][l][c]); g==1 -> Qy row-major.
__global__ __launch_bounds__(256) void k_post(
                       const float* __restrict__ ysb,
                       const float* __restrict__ ow0, const float* __restrict__ ow1,
                       const float* __restrict__ a_h, const float* __restrict__ a_w,
                       const float* __restrict__ w1x, const float* __restrict__ b1x,
                       const float* __restrict__ w1y, const float* __restrict__ b1y,
                       const float* __restrict__ w2x, const float* __restrict__ b2x,
                       const float* __restrict__ w2y, const float* __restrict__ b2y,
                       float* __restrict__ QxT, float* __restrict__ Qy){
  __shared__ float ysS[5][256];
  __shared__ float Sc[5][128];
  __shared__ float Sp[5][128];
  int blk = blockIdx.x;                   // 2*8*32 = 512
  int g = blk>>8, rem = blk&255, b = rem>>5, lt = rem&31, lbase = lt*5;
  int t = threadIdx.x; int c = t&127, kh = t>>7;
  size_t ybase = ((size_t)(g*8+b)*160 + lbase)*256;
  for (int i=t; i<1280; i+=256) ((float*)ysS)[i] = ysb[ybase+i];
  __syncthreads();
  float acc[5];
  // ---- out-proj (K=256 split 2x128) ----
  {
    const float* w = ((g==0)? ow0 : ow1) + (size_t)c*256 + kh*128;
    #pragma unroll
    for (int l=0;l<5;l++) acc[l]=0.f;
    for (int ct=0; ct<16; ct++){
      float4 wa = *(const float4*)(w + ct*8);
      float4 wb = *(const float4*)(w + ct*8 + 4);
      #pragma unroll
      for (int l=0;l<5;l++){
        float4 ua = *(const float4*)&ysS[l][kh*128+ct*8];
        float4 ub = *(const float4*)&ysS[l][kh*128+ct*8+4];
        acc[l] += wa.x*ua.x + wa.y*ua.y + wa.z*ua.z + wa.w*ua.w
                + wb.x*ub.x + wb.y*ub.y + wb.z*ub.z + wb.w*ub.w;
      }
    }
  }
  if (kh==1){ for (int l=0;l<5;l++) Sc[l][c] = acc[l]; }
  __syncthreads();
  if (kh==0){
    const float* a = ((g==0)? a_h : a_w) + ((size_t)(b*128+c))*160 + lbase;
    #pragma unroll
    for (int l=0;l<5;l++) Sp[l][c] = sigm_(acc[l] + Sc[l][c] + a[l]);
  }
  __syncthreads();
  // ---- mlp1 (K=128 split 2x64), gelu ----
  {
    const float* w = ((g==0)? w1x : w1y) + (size_t)c*128 + kh*64;
    #pragma unroll
    for (int l=0;l<5;l++) acc[l]=0.f;
    for (int ct=0; ct<8; ct++){
      float4 wa = *(const float4*)(w + ct*8);
      float4 wb = *(const float4*)(w + ct*8 + 4);
      #pragma unroll
      for (int l=0;l<5;l++){
        float4 ua = *(const float4*)&Sp[l][kh*64+ct*8];
        float4 ub = *(const float4*)&Sp[l][kh*64+ct*8+4];
        acc[l] += wa.x*ua.x + wa.y*ua.y + wa.z*ua.z + wa.w*ua.w
                + wb.x*ub.x + wb.y*ub.y + wb.z*ub.z + wb.w*ub.w;
      }
    }
  }
  if (kh==1){ for (int l=0;l<5;l++) Sc[l][c] = acc[l]; }
  __syncthreads();
  if (kh==0){
    float bb = ((g==0)? b1x : b1y)[c];
    float tv[5];
    #pragma unroll
    for (int l=0;l<5;l++) tv[l] = gelu_(bb + acc[l] + Sc[l][c]);
    __syncthreads();
    #pragma unroll
    for (int l=0;l<5;l++) Sp[l][c] = tv[l];
  } else {
    __syncthreads();
  }
  __syncthreads();
  // ---- mlp2 (K=128 split 2x64) ----
  {
    const float* w = ((g==0)? w2x : w2y) + (size_t)c*128 + kh*64;
    #pragma unroll
    for (int l=0;l<5;l++) acc[l]=0.f;
    for (int ct=0; ct<8; ct++){
      float4 wa = *(const float4*)(w + ct*8);
      float4 wb = *(const float4*)(w + ct*8 + 4);
      #pragma unroll
      for (int l=0;l<5;l++){
        float4 ua = *(const float4*)&Sp[l][kh*64+ct*8];
        float4 ub = *(const float4*)&Sp[l][kh*64+ct*8+4];
        acc[l] += wa.x*ua.x + wa.y*ua.y + wa.z*ua.z + wa.w*ua.w
                + wb.x*ub.x + wb.y*ub.y + wb.z*ub.z + wb.w*ub.w;
      }
    }
  }
  if (kh==1){ for (int l=0;l<5;l++) Sc[l][c] = acc[l]; }
  __syncthreads();
  if (kh==0){
    float bb = ((g==0)? b2x : b2y)[c];
    if (g==0){
      #pragma unroll
      for (int l=0;l<5;l++)
        QxT[((size_t)(b*160 + lbase + l))*128 + c] = bb + acc[l] + Sc[l][c];
    } else {
      size_t orow = ((size_t)(b*128+c))*160 + lbase;
      #pragma unroll
      for (int l=0;l<5;l++) Qy[orow + l] = bb + acc[l] + Sc[l][c];
    }
  }
}

// helper: scale 4-float4 panel regs by gate, write one LDS F buffer [32w][136]
__device__ __forceinline__ void build_F(__hip_bfloat16* Fb, float s, const float4* v,
                                        int wg, int kq){
  #pragma unroll
  for (int u=0;u<4;u++){
    int wr = wg*16 + u*4;
    Fb[(wr+0)*136 + kq] = __float2bfloat16(s*v[u].x);
    Fb[(wr+1)*136 + kq] = __float2bfloat16(s*v[u].y);
    Fb[(wr+2)*136 + kq] = __float2bfloat16(s*v[u].z);
    Fb[(wr+3)*136 + kq] = __float2bfloat16(s*v[u].w);
  }
}

// K7 v5 (MFMA, small-tile + LDS-only barriers) — unchanged from round 9.
__global__ __launch_bounds__(256,4) void k_final_mfma(
                       const float* __restrict__ x,
                       const float* __restrict__ SHT, const float* __restrict__ SW,
                       const float* __restrict__ QxT, const float* __restrict__ Qy,
                       const __hip_bfloat16* __restrict__ adjwb, float* __restrict__ out){
  __shared__ __hip_bfloat16 F[2][32*136];  // double buffer, 2x8.5KB
  int blk0 = blockIdx.x;                   // 1280 = 8 XCD * 160
  int b = blk0 & 7, inner = blk0 >> 3;     // batch b pinned to XCD b
  int ht = inner/5, wq = inner%5;          // ht 0..31, wq 0..4
  int h0 = ht*5;
  int wbase = wq*32;
  int tid = threadIdx.x;
  int kq = tid & 127, wg = tid >> 7;       // staging: k row, w sub-half (16 w)
  int wid = tid>>6, lane = tid&63, quad = lane>>4, l16 = lane&15;

  // gates for the 5 h (coalesced 512B rows)
  float s0[5], s1[5];
  #pragma unroll
  for (int j=0;j<5;j++){
    s0[j] = SHT[((size_t)(b*160+h0+j))*128 + kq];
    s1[j] = QxT[((size_t)(b*160+h0+j))*128 + kq];
  }
  // panels: 4+4 float4, loaded once, reused for all 5 h
  size_t prow = ((size_t)(b*128+kq))*160 + wbase + wg*16;
  const float4* rp0 = (const float4*)(Qy + prow);
  const float4* rp1 = (const float4*)(SW + prow);
  float4 v0[4], v1[4];
  #pragma unroll
  for (int u=0;u<4;u++) v0[u] = rp0[u];
  #pragma unroll
  for (int u=0;u<4;u++) v1[u] = rp1[u];

  build_F(F[0], s0[0], v0, wg, kq);
  LDS_BARRIER();

  // o-row base addresses (o = wid*32 + i*16 + l16)
  size_t rowA = ((size_t)(b*128 + wid*32 + l16))*25600 + wbase + quad*4;
  size_t rowB = rowA + (size_t)16*25600;

  #pragma unroll
  for (int j=0;j<5;j++){
    int h = h0 + j;
    // x prefetch for this h (consumed after MFMA ch1; spans LDS barriers)
    float4 xv[2][2];
    #pragma unroll
    for (int nt=0;nt<2;nt++){
      xv[0][nt] = *(const float4*)(x + rowA + (size_t)h*160 + nt*16);
      xv[1][nt] = *(const float4*)(x + rowB + (size_t)h*160 + nt*16);
    }
    f32x4 acc[2][2];
    #pragma unroll
    for (int i=0;i<2;i++)
      #pragma unroll
      for (int nt=0;nt<2;nt++) acc[i][nt] = (f32x4){0.f,0.f,0.f,0.f};

    // ---- MFMA ch0 (reads F[0]) ----
    {
      short8 bf[2][4];
      #pragma unroll
      for (int i=0;i<2;i++){
        const __hip_bfloat16* bp = adjwb + (size_t)(wid*32 + i*16 + l16)*256 + quad*8;
        #pragma unroll
        for (int kc=0;kc<4;kc++) bf[i][kc] = *(const short8*)(bp + kc*32);
      }
      #pragma unroll
      for (int nt=0; nt<2; nt++){
        const __hip_bfloat16* ap = &F[0][(nt*16 + l16)*136 + quad*8];
        #pragma unroll
        for (int kc=0;kc<4;kc++){
          short8 af = *(const short8*)(ap + kc*32);
          acc[0][nt] = __builtin_amdgcn_mfma_f32_16x16x32_bf16(af, bf[0][kc], acc[0][nt], 0,0,0);
          acc[1][nt] = __builtin_amdgcn_mfma_f32_16x16x32_bf16(af, bf[1][kc], acc[1][nt], 0,0,0);
        }
      }
    }
    // build F[1] = ch1 of this h (F[1] readers finished before last barrier)
    build_F(F[1], s1[j], v1, wg, kq);
    LDS_BARRIER();     // F[1] ready; all waves done reading F[0]

    // ---- MFMA ch1 (reads F[1]) ----
    {
      short8 bf[2][4];
      #pragma unroll
      for (int i=0;i<2;i++){
        const __hip_bfloat16* bp = adjwb + (size_t)(wid*32 + i*16 + l16)*256 + 128 + quad*8;
        #pragma unroll
        for (int kc=0;kc<4;kc++) bf[i][kc] = *(const short8*)(bp + kc*32);
      }
      #pragma unroll
      for (int nt=0; nt<2; nt++){
        const __hip_bfloat16* ap = &F[1][(nt*16 + l16)*136 + quad*8];
        #pragma unroll
        for (int kc=0;kc<4;kc++){
          short8 af = *(const short8*)(ap + kc*32);
          acc[0][nt] = __builtin_amdgcn_mfma_f32_16x16x32_bf16(af, bf[0][kc], acc[0][nt], 0,0,0);
          acc[1][nt] = __builtin_amdgcn_mfma_f32_16x16x32_bf16(af, bf[1][kc], acc[1][nt], 0,0,0);
        }
      }
    }
    // build F[0] for next h (F[0] readers finished before last barrier)
    if (j<4) build_F(F[0], s0[j+1], v0, wg, kq);

    // ---- epilogue: multiply prefetched x, plain float4 stores ----
    #pragma unroll
    for (int i=0;i<2;i++){
      size_t rb = (i? rowB : rowA) + (size_t)h*160;
      #pragma unroll
      for (int nt=0; nt<2; nt++){
        f32x4 a = acc[i][nt];
        float4 xvv = xv[i][nt];
        float4 ov = make_float4(xvv.x*a[0], xvv.y*a[1], xvv.z*a[2], xvv.w*a[3]);
        *(float4*)(out + rb + nt*16) = ov;
      }
    }
    LDS_BARRIER();     // F[0]/F[1] safe for next iter; global ops NOT drained
  }
}

extern "C" void kernel_launch(void* const* d_in, const int* in_sizes, int n_in,
                              void* d_out, int out_size, void* d_ws, size_t ws_size,
                              hipStream_t stream) {
  #define W(i) ((const float*)d_in[i])
  const float* X = W(0);
  float* ws = (float*)d_ws;
  float* xh    = ws;               // 163840
  float* xw    = xh    + 163840;   // 163840
  float* ybuf  = xw    + 163840;   // 20480 (unused; slot kept)
  float* ah    = ybuf  + 20480;    // 163840
  float* aw    = ah    + 163840;   // 163840
  float* xcpre = aw    + 163840;   // 655360 (dead after k_conv; adjwb/SHT/SW alias it)
  float* zb    = xcpre + 655360;   // 655360
  float* xcb   = zb    + 655360;   // 655360
  float* dbc   = xcb   + 655360;   // 102400
  float* ysb   = dbc   + 102400;   // 655360
  float* QxT   = ysb   + 655360;   // 163840 (transposed [b][l][c])
  float* Qy    = QxT   + 163840;   // 163840
  __hip_bfloat16* adjwb = (__hip_bfloat16*)xcpre;  // 64KB = 16384 floats
  float* SHT   = xcpre + 16384;    // 163840 (sigm(a_h), transposed [b][h][c])
  float* SW    = SHT   + 163840;   // 163840 (sigm(a_w), row-major [b][c][w])

  k_means  <<<1024, 320, 0, stream>>>(X, xh, xw);
  k_inproj <<<320,  256, 0, stream>>>(xh, xw, W(20), W(29), xcpre, zb);
  k_conv   <<<2560, 256, 0, stream>>>(xcpre, W(21), W(22), W(30), W(31), xcb);
  k_yx     <<<608,  256, 0, stream>>>(xcb, W(23), W(32), dbc,
                                      xh, xw, W(1), W(2), W(3), W(4), W(5), W(6),
                                      W(7), W(8), W(9), W(10), ah, aw, SHT, SW,
                                      W(19), adjwb);  // after k_conv (xcpre dead)
  k_scan   <<<256,  256, 0, stream>>>(dbc, xcb, zb, W(24), W(25), W(33), W(34),
                                      W(26), W(35), W(27), W(36), ysb);
  k_post   <<<512,  256, 0, stream>>>(ysb, W(28), W(37), ah, aw,
                                      W(11), W(12), W(15), W(16),
                                      W(13), W(14), W(17), W(18), QxT, Qy);
  k_final_mfma<<<1280, 256, 0, stream>>>(X, SHT, SW, QxT, Qy, adjwb, (float*)d_out);
  #undef W
}